// Round 9
// baseline (837.197 us; speedup 1.0000x reference)
//
#include <hip/hip_runtime.h>
#include <math.h>

#define HH 19
#define NG 57
#define GP 20     // padded W row (16B-aligned LDS reads)
#define NB 1024
#define TT 2048

typedef float v4f __attribute__((ext_vector_type(4)));
typedef unsigned u2 __attribute__((ext_vector_type(2)));
typedef float v2f __attribute__((ext_vector_type(2)));

__device__ __forceinline__ float rlf(float v, int l) {
  return __uint_as_float(__builtin_amdgcn_readlane(__float_as_uint(v), l));
}
__device__ __forceinline__ float frcp(float v) { return __builtin_amdgcn_rcpf(v); }
__device__ __forceinline__ float fexp2(float v) {
#if __has_builtin(__builtin_amdgcn_exp2f)
  return __builtin_amdgcn_exp2f(v);
#else
  return exp2f(v);
#endif
}
__device__ __forceinline__ unsigned short f2h(float f) {
  return __builtin_bit_cast(unsigned short, (_Float16)f);
}
__device__ __forceinline__ float h2f(unsigned short u) {
  return (float)__builtin_bit_cast(_Float16, u);
}
__device__ __forceinline__ v2f vfma(v2f a, v2f b, v2f c) {
#if __has_builtin(__builtin_elementwise_fma)
  return __builtin_elementwise_fma(a, b, c);
#else
  v2f r; r.x = fmaf(a.x, b.x, c.x); r.y = fmaf(a.y, b.y, c.y); return r;
#endif
}

#if __has_builtin(__builtin_amdgcn_permlane32_swap)
#define HAVE_PLS 1
__device__ __forceinline__ u2 pls(float x) {
  unsigned u = __float_as_uint(x);
  return __builtin_amdgcn_permlane32_swap(u, u, false, false);
}
#else
#define HAVE_PLS 0
#endif

// ---------------- Kernel 1: x-projection GEMM (throughput-bound) ----------
// xg[t*NB+b][g] = f16( scale_g * (x[t][b]·Wih[g] + bih[g] + (g<38? bhh[g]:0)) )
// scale_g = log2e for r/z rows, 2*log2e for n rows. Fully absorbs biases and
// exp2 prescaling so the recurrence kernel consumes xg directly.
__global__ __launch_bounds__(256) void xg_proj(
    const float* __restrict__ x, const float* __restrict__ Wih,
    const float* __restrict__ bih, const float* __restrict__ bhh,
    unsigned short* __restrict__ xg)
{
  __shared__ __align__(16) float wl[NG][GP];
  __shared__ float cb[NG];
  const float L2E = 1.4426950408889634f;
  for (int idx = threadIdx.x; idx < NG * GP; idx += 256) {
    const int g = idx / GP, k = idx - g * GP;
    const float s = (g < 2 * HH) ? L2E : 2.0f * L2E;
    wl[g][k] = (k < HH) ? Wih[g * HH + k] * s : 0.0f;
  }
  if (threadIdx.x < NG) {
    const int g = threadIdx.x;
    const float s = (g < 2 * HH) ? L2E : 2.0f * L2E;
    cb[g] = (bih[g] + (g < 2 * HH ? bhh[g] : 0.0f)) * s;
  }
  __syncthreads();

  const size_t tid = (size_t)blockIdx.x * 256 + threadIdx.x;   // = t*NB + b
  const float* __restrict__ xr = x + tid * HH;
  float xv[GP];
#pragma unroll
  for (int k = 0; k < HH; ++k) xv[k] = xr[k];
  xv[HH] = 0.0f;

  unsigned short* __restrict__ o = xg + tid * NG;
#pragma unroll 3
  for (int g = 0; g < NG; ++g) {
    float a = cb[g];
#pragma unroll
    for (int q = 0; q < GP; q += 4) {
      const v4f w = *(const v4f*)&wl[g][q];   // uniform addr -> LDS broadcast
      a = fmaf(xv[q + 0], w.x, a);
      a = fmaf(xv[q + 1], w.y, a);
      a = fmaf(xv[q + 2], w.z, a);
      a = fmaf(xv[q + 3], w.w, a);
    }
    o[g] = f2h(a);
  }
}

// ---------------- Kernel 2: recurrence (latency-bound, 1 wave/batch) ------
// 57-lane spread as round 8. Per step: ONE 2B lane-parallel xg load (depth-8
// prefetch), 19-fma h-dot, activations, 2 permlane swaps + 1 z-bpermute,
// 19 readlanes, out-projection as filler. No x-dot, no x broadcast.
__global__ void __launch_bounds__(64)
__attribute__((amdgpu_waves_per_eu(1, 1)))
gru_rec(const unsigned short* __restrict__ xg, const float* __restrict__ Whh,
        const float* __restrict__ bhh, const float* __restrict__ Wout,
        const float* __restrict__ bout, float* __restrict__ out)
{
  const int b = blockIdx.x;
  const int lane = threadIdx.x;
  const float L2E = 1.4426950408889634f;

  int row;
  if (lane < 32)      row = lane;          // r-rows 0-18 (h owners), z-rows 19-31
  else if (lane < 51) row = lane + 6;      // n-rows 38-56
  else if (lane < 57) row = lane - 19;     // z-rows 32-37
  else                row = 37;
  const bool isn = (row >= 2 * HH);
  const float scale = isn ? (2.0f * L2E) : L2E;

  float wh[HH], wo[HH];
#pragma unroll
  for (int k = 0; k < HH; ++k) {
    wh[k] = Whh[row * HH + k] * scale;
    wo[k] = Wout[k];
  }
  const float ah0 = isn ? bhh[row] * scale : 0.0f;  // n keeps bhh inside r*(...)
  const float bo  = bout[0];

  const int il = lane < HH ? lane : HH - 1;
  const int zaddr = ((il < 13) ? (19 + il) : (38 + il)) * 4;

#if HAVE_PLS
  bool loIsX;
  {
    unsigned l = (unsigned)lane;
    u2 pr = __builtin_amdgcn_permlane32_swap(l, l, false, false);
    loIsX = ((unsigned)__builtin_amdgcn_readlane((int)pr.x, 32) < 32u);
  }
#define LOBCAST(val, dst) do { u2 _s = pls(val);                        \
    dst = __uint_as_float(loIsX ? _s.x : _s.y); } while (0)
#define HIBCAST(val, dst) do { u2 _s = pls(val);                        \
    dst = __uint_as_float(loIsX ? _s.y : _s.x); } while (0)
#else
  const int loaddr = (lane & 31) * 4;
  const int hiaddr = ((lane & 31) | 32) * 4;
#define LOBCAST(val, dst) dst = __uint_as_float((unsigned)              \
    __builtin_amdgcn_ds_bpermute(loaddr, (int)__float_as_uint(val)))
#define HIBCAST(val, dst) dst = __uint_as_float((unsigned)              \
    __builtin_amdgcn_ds_bpermute(hiaddr, (int)__float_as_uint(val)))
#endif

  float h = 0.0f;       // lane i (<19) owns h_i
  float sh[HH];         // wave-uniform h copy (readlane -> SGPRs)
#pragma unroll
  for (int k = 0; k < HH; ++k) sh[k] = 0.0f;

  const unsigned short* __restrict__ xb = xg + (size_t)b * NG + row;

#define LOADX(dst, trow) do {                                           \
    dst = xb[(size_t)(trow) * (NB * NG)];                               \
  } while (0)

  unsigned short s0, s1, s2, s3, s4, s5, s6, s7;
  LOADX(s0, 0); LOADX(s1, 1); LOADX(s2, 2); LOADX(s3, 3);
  LOADX(s4, 4); LOADX(s5, 5); LOADX(s6, 6); LOADX(s7, 7);

#define BODY(tcur, slot) do {                                           \
    const float xv = h2f(slot);                                         \
    float a0 = ah0, a1 = 0.0f, a2 = 0.0f, a3 = 0.0f;                    \
    _Pragma("unroll")                                                   \
    for (int _k = 0; _k < HH; ++_k) {                                   \
      if ((_k & 3) == 0) a0 = fmaf(sh[_k], wh[_k], a0);                 \
      if ((_k & 3) == 1) a1 = fmaf(sh[_k], wh[_k], a1);                 \
      if ((_k & 3) == 2) a2 = fmaf(sh[_k], wh[_k], a2);                 \
      if ((_k & 3) == 3) a3 = fmaf(sh[_k], wh[_k], a3);                 \
    }                                                                   \
    const float preh = (a0 + a1) + (a2 + a3);                           \
    const float pre  = xv + preh;                                       \
    const float sig  = frcp(1.0f + fexp2(-pre));                        \
    const int zzi = __builtin_amdgcn_ds_bpermute(                       \
        zaddr, (int)__float_as_uint(sig));                              \
    float rr; LOBCAST(sig, rr);                                         \
    const float npre = fmaf(rr, preh, xv);                              \
    const float nn = fmaf(-2.0f, frcp(fexp2(npre) + 1.0f), 1.0f);       \
    float nh; HIBCAST(nn, nh);                                          \
    const float zz = __uint_as_float((unsigned)zzi);                    \
    h = fmaf(zz, h - nh, nh);                                           \
    _Pragma("unroll")                                                   \
    for (int _k = 0; _k < HH; ++_k) sh[_k] = rlf(h, _k);                \
    float o0 = bo, o1 = 0.0f, o2 = 0.0f, o3 = 0.0f;                     \
    _Pragma("unroll")                                                   \
    for (int _k = 0; _k < HH; ++_k) {                                   \
      if ((_k & 3) == 0) o0 = fmaf(sh[_k], wo[_k], o0);                 \
      if ((_k & 3) == 1) o1 = fmaf(sh[_k], wo[_k], o1);                 \
      if ((_k & 3) == 2) o2 = fmaf(sh[_k], wo[_k], o2);                 \
      if ((_k & 3) == 3) o3 = fmaf(sh[_k], wo[_k], o3);                 \
    }                                                                   \
    if (lane == 0) out[(size_t)(tcur) * NB + b] = (o0 + o1) + (o2 + o3);\
    { const int _tl = ((tcur) + 8 < TT) ? (tcur) + 8 : TT - 1;          \
      LOADX(slot, _tl); }                                               \
  } while (0)

  for (int t = 0; t < TT; t += 8) {
    BODY(t + 0, s0); BODY(t + 1, s1); BODY(t + 2, s2); BODY(t + 3, s3);
    BODY(t + 4, s4); BODY(t + 5, s5); BODY(t + 6, s6); BODY(t + 7, s7);
  }

#undef LOADX
#undef BODY
#undef LOBCAST
#undef HIBCAST
}

// ---------------- Fallback: round-8 fused kernel (if ws too small) --------
__global__ void __launch_bounds__(64)
__attribute__((amdgpu_waves_per_eu(1, 1)))
gru57_v4(const float* __restrict__ x, const float* __restrict__ Wih,
         const float* __restrict__ Whh, const float* __restrict__ bih,
         const float* __restrict__ bhh, const float* __restrict__ Wout,
         const float* __restrict__ bout, float* __restrict__ out)
{
  const int b = blockIdx.x;
  const int lane = threadIdx.x;
  const float L2E = 1.4426950408889634f;

  int row;
  if (lane < 32)      row = lane;
  else if (lane < 51) row = lane + 6;
  else if (lane < 57) row = lane - 19;
  else                row = 37;
  const bool isn = (row >= 2 * HH);
  const float scale = isn ? (2.0f * L2E) : L2E;

  v2f wx2[10], wh2[10], wo2[10];
#pragma unroll
  for (int j = 0; j < 10; ++j) {
    const int k0 = 2 * j, k1 = 2 * j + 1;
    wx2[j].x = Wih[row * HH + k0] * scale;
    wx2[j].y = (k1 < HH) ? Wih[row * HH + k1] * scale : 0.0f;
    wh2[j].x = Whh[row * HH + k0] * scale;
    wh2[j].y = (k1 < HH) ? Whh[row * HH + k1] * scale : 0.0f;
    wo2[j].x = Wout[k0];
    wo2[j].y = (k1 < HH) ? Wout[k1] : 0.0f;
  }
  const float bxv = bih[row] * scale, bhv = bhh[row] * scale;
  const float ax0 = isn ? bxv : (bxv + bhv);
  const float ah0 = isn ? bhv : 0.0f;
  const float bo  = bout[0];

  const int il = lane < HH ? lane : HH - 1;
  const int zaddr = ((il < 13) ? (19 + il) : (38 + il)) * 4;

#if HAVE_PLS
  bool loIsX;
  {
    unsigned l = (unsigned)lane;
    u2 pr = __builtin_amdgcn_permlane32_swap(l, l, false, false);
    loIsX = ((unsigned)__builtin_amdgcn_readlane((int)pr.x, 32) < 32u);
  }
#define LOBCAST(val, dst) do { u2 _s = pls(val);                        \
    dst = __uint_as_float(loIsX ? _s.x : _s.y); } while (0)
#define HIBCAST(val, dst) do { u2 _s = pls(val);                        \
    dst = __uint_as_float(loIsX ? _s.y : _s.x); } while (0)
#else
  const int loaddr = (lane & 31) * 4;
  const int hiaddr = ((lane & 31) | 32) * 4;
#define LOBCAST(val, dst) dst = __uint_as_float((unsigned)              \
    __builtin_amdgcn_ds_bpermute(loaddr, (int)__float_as_uint(val)))
#define HIBCAST(val, dst) dst = __uint_as_float((unsigned)              \
    __builtin_amdgcn_ds_bpermute(hiaddr, (int)__float_as_uint(val)))
#endif

  float h = 0.0f;
  v2f sh2[10];
#pragma unroll
  for (int j = 0; j < 10; ++j) { sh2[j].x = 0.0f; sh2[j].y = 0.0f; }

  const int kx = lane < HH ? lane : HH - 1;
  const float* __restrict__ xbase = x + (size_t)b * HH + kx;

#define LOADXF(dst, trow) do { dst = xbase[(size_t)(trow) * (NB * HH)]; } while (0)
#define XBCAST(slot, xu) do {                                           \
    _Pragma("unroll")                                                   \
    for (int _j = 0; _j < 9; ++_j) {                                    \
      xu[_j].x = rlf(slot, 2 * _j);                                     \
      xu[_j].y = rlf(slot, 2 * _j + 1);                                 \
    }                                                                   \
    xu[9].x = rlf(slot, 18); xu[9].y = 0.0f;                            \
  } while (0)
#define XDOT(xu, dstvar) do {                                           \
    v2f _aA = {ax0, 0.0f}, _aB = {0.0f, 0.0f};                          \
    _Pragma("unroll")                                                   \
    for (int _j = 0; _j < 5; ++_j)  _aA = vfma(xu[_j], wx2[_j], _aA);   \
    _Pragma("unroll")                                                   \
    for (int _j = 5; _j < 10; ++_j) _aB = vfma(xu[_j], wx2[_j], _aB);   \
    const v2f _s = _aA + _aB;                                           \
    dstvar = _s.x + _s.y;                                               \
  } while (0)

  float xlA, xlB, xlC, xlD;
  LOADXF(xlA, 0); LOADXF(xlB, 1); LOADXF(xlC, 2); LOADXF(xlD, 3);
  float prex;
  { v2f xu0[10]; XBCAST(xlA, xu0); XDOT(xu0, prex); }

#define BODYF(tcur, nslot, lslot) do {                                  \
    v2f ahA = {ah0, 0.0f}, ahB = {0.0f, 0.0f};                          \
    _Pragma("unroll")                                                   \
    for (int _j = 0; _j < 5; ++_j)  ahA = vfma(sh2[_j], wh2[_j], ahA);  \
    _Pragma("unroll")                                                   \
    for (int _j = 5; _j < 10; ++_j) ahB = vfma(sh2[_j], wh2[_j], ahB);  \
    float prexN;                                                        \
    { v2f _xu[10]; XBCAST(nslot, _xu); XDOT(_xu, prexN); }              \
    { const int _tl = ((tcur) + 4 < TT) ? (tcur) + 4 : TT - 1;          \
      LOADXF(lslot, _tl); }                                             \
    const v2f ahv = ahA + ahB;                                          \
    const float preh = ahv.x + ahv.y;                                   \
    const float pre  = prex + preh;                                     \
    const float sig  = frcp(1.0f + fexp2(-pre));                        \
    const int zzi = __builtin_amdgcn_ds_bpermute(                       \
        zaddr, (int)__float_as_uint(sig));                              \
    float rr; LOBCAST(sig, rr);                                         \
    const float npre = fmaf(rr, preh, prex);                            \
    const float nn = fmaf(-2.0f, frcp(fexp2(npre) + 1.0f), 1.0f);       \
    float nh; HIBCAST(nn, nh);                                          \
    const float zz = __uint_as_float((unsigned)zzi);                    \
    h = fmaf(zz, h - nh, nh);                                           \
    _Pragma("unroll")                                                   \
    for (int _j = 0; _j < 9; ++_j) {                                    \
      sh2[_j].x = rlf(h, 2 * _j);                                       \
      sh2[_j].y = rlf(h, 2 * _j + 1);                                   \
    }                                                                   \
    sh2[9].x = rlf(h, 18); sh2[9].y = 0.0f;                             \
    v2f oA = {bo, 0.0f}, oB = {0.0f, 0.0f};                             \
    _Pragma("unroll")                                                   \
    for (int _j = 0; _j < 5; ++_j)  oA = vfma(sh2[_j], wo2[_j], oA);    \
    _Pragma("unroll")                                                   \
    for (int _j = 5; _j < 10; ++_j) oB = vfma(sh2[_j], wo2[_j], oB);    \
    const v2f ov = oA + oB;                                             \
    if (lane == 0) out[(size_t)(tcur) * NB + b] = ov.x + ov.y;          \
    prex = prexN;                                                       \
  } while (0)

  for (int t = 0; t < TT; t += 4) {
    BODYF(t + 0, xlB, xlA);
    BODYF(t + 1, xlC, xlB);
    BODYF(t + 2, xlD, xlC);
    BODYF(t + 3, xlA, xlD);
  }

#undef LOADXF
#undef XBCAST
#undef XDOT
#undef BODYF
#undef LOBCAST
#undef HIBCAST
}

extern "C" void kernel_launch(void* const* d_in, const int* in_sizes, int n_in,
                              void* d_out, int out_size, void* d_ws, size_t ws_size,
                              hipStream_t stream) {
  const float* x    = (const float*)d_in[0];
  const float* Wih  = (const float*)d_in[1];
  const float* Whh  = (const float*)d_in[2];
  const float* bih  = (const float*)d_in[3];
  const float* bhh  = (const float*)d_in[4];
  const float* Wout = (const float*)d_in[5];
  const float* bout = (const float*)d_in[6];
  float* out = (float*)d_out;

  const size_t need = (size_t)TT * NB * NG * sizeof(unsigned short);  // 239 MB
  if (ws_size >= need) {
    unsigned short* xgws = (unsigned short*)d_ws;
    xg_proj<<<dim3((TT * NB) / 256), dim3(256), 0, stream>>>(
        x, Wih, bih, bhh, xgws);
    gru_rec<<<dim3(NB), dim3(64), 0, stream>>>(
        xgws, Whh, bhh, Wout, bout, out);
  } else {
    gru57_v4<<<dim3(NB), dim3(64), 0, stream>>>(
        x, Wih, Whh, bih, bhh, Wout, bout, out);
  }
}

// Round 10
// 688.372 us; speedup vs baseline: 1.2162x; 1.2162x over previous
//
#include <hip/hip_runtime.h>
#include <math.h>

#define HH 19
#define NG 57
#define NB 1024
#define TT 2048

typedef float v2f __attribute__((ext_vector_type(2)));
typedef float v4f __attribute__((ext_vector_type(4)));
typedef unsigned u2 __attribute__((ext_vector_type(2)));

__device__ __forceinline__ float rlf(float v, int l) {
  return __uint_as_float(__builtin_amdgcn_readlane(__float_as_uint(v), l));
}
__device__ __forceinline__ float frcp(float v) { return __builtin_amdgcn_rcpf(v); }
__device__ __forceinline__ float fexp2(float v) {
#if __has_builtin(__builtin_amdgcn_exp2f)
  return __builtin_amdgcn_exp2f(v);
#else
  return exp2f(v);
#endif
}
__device__ __forceinline__ unsigned short f2h(float f) {
  return __builtin_bit_cast(unsigned short, (_Float16)f);
}
__device__ __forceinline__ float h2f(unsigned short u) {
  return (float)__builtin_bit_cast(_Float16, u);
}
__device__ __forceinline__ v2f mk2(float a, float b) { v2f r; r.x = a; r.y = b; return r; }
__device__ __forceinline__ v2f vfma(v2f a, v2f b, v2f c) {
#if __has_builtin(__builtin_elementwise_fma)
  return __builtin_elementwise_fma(a, b, c);
#else
  v2f r; r.x = fmaf(a.x, b.x, c.x); r.y = fmaf(a.y, b.y, c.y); return r;
#endif
}

#if __has_builtin(__builtin_amdgcn_permlane32_swap)
#define HAVE_PLS 1
__device__ __forceinline__ u2 pls(float x) {
  unsigned u = __float_as_uint(x);
  return __builtin_amdgcn_permlane32_swap(u, u, false, false);
}
#else
#define HAVE_PLS 0
#endif

// ---------------- K1: x-projection, gate-per-lane -------------------------
// xg[pair][g] = f16( scale_g*(x[pair]·Wih[g]) + cb_g ), slot-g layout,
// row stride 114B. scale: g<38 -> -log2e (r,z), g>=38 -> +2log2e (n).
// cb folds bih (+bhh for r/z). Lane g holds its weight row in VGPRs; the
// x row address is wave-uniform -> scalar loads; store = ONE coalesced
// 114B ushort-store per pair (fixes round-9's scattered-store disaster).
__global__ __launch_bounds__(256) void xg_proj2(
    const float* __restrict__ x, const float* __restrict__ Wih,
    const float* __restrict__ bih, const float* __restrict__ bhh,
    unsigned short* __restrict__ xg)
{
  const int lane = threadIdx.x & 63;
  const int wv = __builtin_amdgcn_readfirstlane((int)(threadIdx.x >> 6));
  const int g = lane < NG ? lane : NG - 1;
  const float L2E = 1.4426950408889634f;
  const float scale = (g < 2 * HH) ? -L2E : 2.0f * L2E;

  float w[HH];
#pragma unroll
  for (int k = 0; k < HH; ++k) w[k] = Wih[g * HH + k] * scale;
  const float cbv = (bih[g] + (g < 2 * HH ? bhh[g] : 0.0f)) * scale;

  const size_t pair0 = ((size_t)blockIdx.x * 4 + wv) * 64;
  for (int p = 0; p < 64; ++p) {
    const size_t pair = pair0 + p;
    const float* __restrict__ xr = x + pair * HH;   // wave-uniform address
    float a = cbv;
#pragma unroll
    for (int k = 0; k < HH; ++k) a = fmaf(xr[k], w[k], a);
    if (lane < NG) xg[pair * NG + g] = f2h(a);
  }
}

// ---------------- K2: recurrence, all-local lanes --------------------------
// Lane i<19 computes r_i, z_i, n_i, h_i locally (30 pk_fma for 57 MACs).
// NO cross-lane ops at all; h broadcast via LDS: 1 ds_write + 5 uniform
// ds_read_b128. Out-projection inline (pk), pipelined one step behind
// (it consumes the h_{t-1} broadcast done at the top of step t).
__global__ void __launch_bounds__(64)
__attribute__((amdgpu_waves_per_eu(1, 1)))
gru_rec2(const unsigned short* __restrict__ xg, const float* __restrict__ Whh,
         const float* __restrict__ bhh, const float* __restrict__ Wout,
         const float* __restrict__ bout, float* __restrict__ out)
{
  __shared__ __align__(16) float hsh[64];
  const int b = blockIdx.x;
  const int lane = threadIdx.x;
  const int i = lane < HH ? lane : HH - 1;
  const float L2E = 1.4426950408889634f;

  // per-lane weight rows, pk pairs (pad .y = 0 at j=9)
  v2f wr2[10], wz2[10], wn2[10], wo2[10];
#pragma unroll
  for (int j = 0; j < 10; ++j) {
    const int k0 = 2 * j, k1 = 2 * j + 1;
    wr2[j].x = -L2E * Whh[i * HH + k0];
    wr2[j].y = (k1 < HH) ? -L2E * Whh[i * HH + k1] : 0.0f;
    wz2[j].x = -L2E * Whh[(HH + i) * HH + k0];
    wz2[j].y = (k1 < HH) ? -L2E * Whh[(HH + i) * HH + k1] : 0.0f;
    wn2[j].x = 2.0f * L2E * Whh[(2 * HH + i) * HH + k0];
    wn2[j].y = (k1 < HH) ? 2.0f * L2E * Whh[(2 * HH + i) * HH + k1] : 0.0f;
    wo2[j].x = Wout[k0];
    wo2[j].y = (k1 < HH) ? Wout[k1] : 0.0f;
  }
  const float bnv = 2.0f * L2E * bhh[2 * HH + i];  // n's h-side bias (in r*(...))
  const float bo = bout[0];

  float h = 0.0f;   // lane i owns h_i (f32 throughout)

  const unsigned short* __restrict__ xb = xg + (size_t)b * NG;
#define LR(dst, t) dst = xb[(size_t)(t) * (NB * NG) + i]
#define LZ(dst, t) dst = xb[(size_t)(t) * (NB * NG) + HH + i]
#define LN(dst, t) dst = xb[(size_t)(t) * (NB * NG) + 2 * HH + i]

  unsigned short r0,r1,r2,r3,r4,r5,r6,r7;
  unsigned short z0,z1,z2,z3,z4,z5,z6,z7;
  unsigned short n0,n1,n2,n3,n4,n5,n6,n7;
  LR(r0,0); LZ(z0,0); LN(n0,0);  LR(r1,1); LZ(z1,1); LN(n1,1);
  LR(r2,2); LZ(z2,2); LN(n2,2);  LR(r3,3); LZ(z3,3); LN(n3,3);
  LR(r4,4); LZ(z4,4); LN(n4,4);  LR(r5,5); LZ(z5,5); LN(n5,5);
  LR(r6,6); LZ(z6,6); LN(n6,6);  LR(r7,7); LZ(z7,7); LN(n7,7);

#define BODY(tcur, rs, zs, ns) do {                                      \
    /* broadcast h_{t-1}: per-lane write, uniform b128 reads */          \
    hsh[lane] = (lane < HH) ? h : 0.0f;                                  \
    const v4f q0 = *(const v4f*)&hsh[0];                                 \
    const v4f q1 = *(const v4f*)&hsh[4];                                 \
    const v4f q2 = *(const v4f*)&hsh[8];                                 \
    const v4f q3 = *(const v4f*)&hsh[12];                                \
    const v4f q4 = *(const v4f*)&hsh[16];                                \
    v2f sh2[10];                                                         \
    sh2[0]=mk2(q0.x,q0.y); sh2[1]=mk2(q0.z,q0.w);                        \
    sh2[2]=mk2(q1.x,q1.y); sh2[3]=mk2(q1.z,q1.w);                        \
    sh2[4]=mk2(q2.x,q2.y); sh2[5]=mk2(q2.z,q2.w);                        \
    sh2[6]=mk2(q3.x,q3.y); sh2[7]=mk2(q3.z,q3.w);                        \
    sh2[8]=mk2(q4.x,q4.y); sh2[9]=mk2(q4.z,q4.w);                        \
    /* out-projection of h_{t-1} (one step behind) */                    \
    v2f oA = mk2(bo, 0.0f), oB = mk2(0.0f, 0.0f);                        \
    _Pragma("unroll")                                                    \
    for (int _j = 0; _j < 5; ++_j)  oA = vfma(sh2[_j], wo2[_j], oA);     \
    _Pragma("unroll")                                                    \
    for (int _j = 5; _j < 10; ++_j) oB = vfma(sh2[_j], wo2[_j], oB);     \
    const v2f ov = oA + oB;                                              \
    if (lane == 0) {                                                     \
      const int tp = (tcur) > 0 ? (tcur) - 1 : 0;                        \
      out[(size_t)tp * NB + b] = ov.x + ov.y;                            \
    }                                                                    \
    /* gates: three local dots, 2 pk-acc streams each */                 \
    const float xvr = h2f(rs), xvz = h2f(zs), xvn = h2f(ns);             \
    v2f aR0 = mk2(xvr, 0.0f), aR1 = mk2(0.0f, 0.0f);                     \
    v2f aZ0 = mk2(xvz, 0.0f), aZ1 = mk2(0.0f, 0.0f);                     \
    v2f aN0 = mk2(bnv, 0.0f), aN1 = mk2(0.0f, 0.0f);                     \
    _Pragma("unroll")                                                    \
    for (int _j = 0; _j < 5; ++_j) {                                     \
      aR0 = vfma(sh2[_j], wr2[_j], aR0);                                 \
      aZ0 = vfma(sh2[_j], wz2[_j], aZ0);                                 \
      aN0 = vfma(sh2[_j], wn2[_j], aN0);                                 \
    }                                                                    \
    _Pragma("unroll")                                                    \
    for (int _j = 5; _j < 10; ++_j) {                                    \
      aR1 = vfma(sh2[_j], wr2[_j], aR1);                                 \
      aZ1 = vfma(sh2[_j], wz2[_j], aZ1);                                 \
      aN1 = vfma(sh2[_j], wn2[_j], aN1);                                 \
    }                                                                    \
    const v2f mR = aR0 + aR1, mZ = aZ0 + aZ1, mN = aN0 + aN1;            \
    const float preR = mR.x + mR.y;   /* -log2e * (r pre-act) */         \
    const float preZ = mZ.x + mZ.y;   /* -log2e * (z pre-act) */         \
    const float preN = mN.x + mN.y;   /* 2log2e * (Whn.h + bhn) */       \
    const float rr = frcp(fexp2(preR) + 1.0f);   /* sigmoid */           \
    const float zz = frcp(fexp2(preZ) + 1.0f);                           \
    const float argP = fmaf(rr, preN, xvn);      /* 2log2e * npre */     \
    const float D = frcp(fexp2(argP) + 1.0f);                            \
    const float nn = fmaf(-2.0f, D, 1.0f);       /* tanh(npre) */        \
    h = fmaf(zz, h - nn, nn);                                            \
    { const int tl = ((tcur) + 8 < TT) ? (tcur) + 8 : TT - 1;            \
      LR(rs, tl); LZ(zs, tl); LN(ns, tl); }                              \
  } while (0)

  for (int t = 0; t < TT; t += 8) {
    BODY(t + 0, r0, z0, n0); BODY(t + 1, r1, z1, n1);
    BODY(t + 2, r2, z2, n2); BODY(t + 3, r3, z3, n3);
    BODY(t + 4, r4, z4, n4); BODY(t + 5, r5, z5, n5);
    BODY(t + 6, r6, z6, n6); BODY(t + 7, r7, z7, n7);
  }

  // epilogue: out[TT-1] from final h
  hsh[lane] = (lane < HH) ? h : 0.0f;
  {
    const v4f q0 = *(const v4f*)&hsh[0];
    const v4f q1 = *(const v4f*)&hsh[4];
    const v4f q2 = *(const v4f*)&hsh[8];
    const v4f q3 = *(const v4f*)&hsh[12];
    const v4f q4 = *(const v4f*)&hsh[16];
    v2f sh2[10];
    sh2[0]=mk2(q0.x,q0.y); sh2[1]=mk2(q0.z,q0.w);
    sh2[2]=mk2(q1.x,q1.y); sh2[3]=mk2(q1.z,q1.w);
    sh2[4]=mk2(q2.x,q2.y); sh2[5]=mk2(q2.z,q2.w);
    sh2[6]=mk2(q3.x,q3.y); sh2[7]=mk2(q3.z,q3.w);
    sh2[8]=mk2(q4.x,q4.y); sh2[9]=mk2(q4.z,q4.w);
    v2f oA = mk2(bo, 0.0f), oB = mk2(0.0f, 0.0f);
#pragma unroll
    for (int j = 0; j < 5; ++j)  oA = vfma(sh2[j], wo2[j], oA);
#pragma unroll
    for (int j = 5; j < 10; ++j) oB = vfma(sh2[j], wo2[j], oB);
    const v2f ov = oA + oB;
    if (lane == 0) out[(size_t)(TT - 1) * NB + b] = ov.x + ov.y;
  }
#undef LR
#undef LZ
#undef LN
#undef BODY
}

// ---------------- Fallback: round-8 fused kernel (proven, 555us) ----------
__global__ void __launch_bounds__(64)
__attribute__((amdgpu_waves_per_eu(1, 1)))
gru57_v4(const float* __restrict__ x, const float* __restrict__ Wih,
         const float* __restrict__ Whh, const float* __restrict__ bih,
         const float* __restrict__ bhh, const float* __restrict__ Wout,
         const float* __restrict__ bout, float* __restrict__ out)
{
  const int b = blockIdx.x;
  const int lane = threadIdx.x;
  const float L2E = 1.4426950408889634f;

  int row;
  if (lane < 32)      row = lane;
  else if (lane < 51) row = lane + 6;
  else if (lane < 57) row = lane - 19;
  else                row = 37;
  const bool isn = (row >= 2 * HH);
  const float scale = isn ? (2.0f * L2E) : L2E;

  v2f wx2[10], wh2[10], wo2[10];
#pragma unroll
  for (int j = 0; j < 10; ++j) {
    const int k0 = 2 * j, k1 = 2 * j + 1;
    wx2[j].x = Wih[row * HH + k0] * scale;
    wx2[j].y = (k1 < HH) ? Wih[row * HH + k1] * scale : 0.0f;
    wh2[j].x = Whh[row * HH + k0] * scale;
    wh2[j].y = (k1 < HH) ? Whh[row * HH + k1] * scale : 0.0f;
    wo2[j].x = Wout[k0];
    wo2[j].y = (k1 < HH) ? Wout[k1] : 0.0f;
  }
  const float bxv = bih[row] * scale, bhv = bhh[row] * scale;
  const float ax0 = isn ? bxv : (bxv + bhv);
  const float ah0 = isn ? bhv : 0.0f;
  const float bo  = bout[0];

  const int il = lane < HH ? lane : HH - 1;
  const int zaddr = ((il < 13) ? (19 + il) : (38 + il)) * 4;

#if HAVE_PLS
  bool loIsX;
  {
    unsigned l = (unsigned)lane;
    u2 pr = __builtin_amdgcn_permlane32_swap(l, l, false, false);
    loIsX = ((unsigned)__builtin_amdgcn_readlane((int)pr.x, 32) < 32u);
  }
#define LOBCAST(val, dst) do { u2 _s = pls(val);                        \
    dst = __uint_as_float(loIsX ? _s.x : _s.y); } while (0)
#define HIBCAST(val, dst) do { u2 _s = pls(val);                        \
    dst = __uint_as_float(loIsX ? _s.y : _s.x); } while (0)
#else
  const int loaddr = (lane & 31) * 4;
  const int hiaddr = ((lane & 31) | 32) * 4;
#define LOBCAST(val, dst) dst = __uint_as_float((unsigned)              \
    __builtin_amdgcn_ds_bpermute(loaddr, (int)__float_as_uint(val)))
#define HIBCAST(val, dst) dst = __uint_as_float((unsigned)              \
    __builtin_amdgcn_ds_bpermute(hiaddr, (int)__float_as_uint(val)))
#endif

  float h = 0.0f;
  v2f sh2[10];
#pragma unroll
  for (int j = 0; j < 10; ++j) { sh2[j].x = 0.0f; sh2[j].y = 0.0f; }

  const int kx = lane < HH ? lane : HH - 1;
  const float* __restrict__ xbase = x + (size_t)b * HH + kx;

#define LOADXF(dst, trow) do { dst = xbase[(size_t)(trow) * (NB * HH)]; } while (0)
#define XBCAST(slot, xu) do {                                           \
    _Pragma("unroll")                                                   \
    for (int _j = 0; _j < 9; ++_j) {                                    \
      xu[_j].x = rlf(slot, 2 * _j);                                     \
      xu[_j].y = rlf(slot, 2 * _j + 1);                                 \
    }                                                                   \
    xu[9].x = rlf(slot, 18); xu[9].y = 0.0f;                            \
  } while (0)
#define XDOT(xu, dstvar) do {                                           \
    v2f _aA = mk2(ax0, 0.0f), _aB = mk2(0.0f, 0.0f);                    \
    _Pragma("unroll")                                                   \
    for (int _j = 0; _j < 5; ++_j)  _aA = vfma(xu[_j], wx2[_j], _aA);   \
    _Pragma("unroll")                                                   \
    for (int _j = 5; _j < 10; ++_j) _aB = vfma(xu[_j], wx2[_j], _aB);   \
    const v2f _s = _aA + _aB;                                           \
    dstvar = _s.x + _s.y;                                               \
  } while (0)

  float xlA, xlB, xlC, xlD;
  LOADXF(xlA, 0); LOADXF(xlB, 1); LOADXF(xlC, 2); LOADXF(xlD, 3);
  float prex;
  { v2f xu0[10]; XBCAST(xlA, xu0); XDOT(xu0, prex); }

#define BODYF(tcur, nslot, lslot) do {                                  \
    v2f ahA = mk2(ah0, 0.0f), ahB = mk2(0.0f, 0.0f);                    \
    _Pragma("unroll")                                                   \
    for (int _j = 0; _j < 5; ++_j)  ahA = vfma(sh2[_j], wh2[_j], ahA);  \
    _Pragma("unroll")                                                   \
    for (int _j = 5; _j < 10; ++_j) ahB = vfma(sh2[_j], wh2[_j], ahB);  \
    float prexN;                                                        \
    { v2f _xu[10]; XBCAST(nslot, _xu); XDOT(_xu, prexN); }              \
    { const int _tl = ((tcur) + 4 < TT) ? (tcur) + 4 : TT - 1;          \
      LOADXF(lslot, _tl); }                                             \
    const v2f ahv = ahA + ahB;                                          \
    const float preh = ahv.x + ahv.y;                                   \
    const float pre  = prex + preh;                                     \
    const float sig  = frcp(1.0f + fexp2(-pre));                        \
    const int zzi = __builtin_amdgcn_ds_bpermute(                       \
        zaddr, (int)__float_as_uint(sig));                              \
    float rr; LOBCAST(sig, rr);                                         \
    const float npre = fmaf(rr, preh, prex);                            \
    const float nn = fmaf(-2.0f, frcp(fexp2(npre) + 1.0f), 1.0f);       \
    float nh; HIBCAST(nn, nh);                                          \
    const float zz = __uint_as_float((unsigned)zzi);                    \
    h = fmaf(zz, h - nh, nh);                                           \
    _Pragma("unroll")                                                   \
    for (int _j = 0; _j < 9; ++_j) {                                    \
      sh2[_j].x = rlf(h, 2 * _j);                                       \
      sh2[_j].y = rlf(h, 2 * _j + 1);                                   \
    }                                                                   \
    sh2[9].x = rlf(h, 18); sh2[9].y = 0.0f;                             \
    v2f oA = mk2(bo, 0.0f), oB = mk2(0.0f, 0.0f);                       \
    _Pragma("unroll")                                                   \
    for (int _j = 0; _j < 5; ++_j)  oA = vfma(sh2[_j], wo2[_j], oA);    \
    _Pragma("unroll")                                                   \
    for (int _j = 5; _j < 10; ++_j) oB = vfma(sh2[_j], wo2[_j], oB);    \
    const v2f ov = oA + oB;                                             \
    if (lane == 0) out[(size_t)(tcur) * NB + b] = ov.x + ov.y;          \
    prex = prexN;                                                       \
  } while (0)

  for (int t = 0; t < TT; t += 4) {
    BODYF(t + 0, xlB, xlA);
    BODYF(t + 1, xlC, xlB);
    BODYF(t + 2, xlD, xlC);
    BODYF(t + 3, xlA, xlD);
  }

#undef LOADXF
#undef XBCAST
#undef XDOT
#undef BODYF
#undef LOBCAST
#undef HIBCAST
}

extern "C" void kernel_launch(void* const* d_in, const int* in_sizes, int n_in,
                              void* d_out, int out_size, void* d_ws, size_t ws_size,
                              hipStream_t stream) {
  const float* x    = (const float*)d_in[0];
  const float* Wih  = (const float*)d_in[1];
  const float* Whh  = (const float*)d_in[2];
  const float* bih  = (const float*)d_in[3];
  const float* bhh  = (const float*)d_in[4];
  const float* Wout = (const float*)d_in[5];
  const float* bout = (const float*)d_in[6];
  float* out = (float*)d_out;

  const size_t need = (size_t)TT * NB * NG * sizeof(unsigned short);
  if (ws_size >= need) {
    unsigned short* xgws = (unsigned short*)d_ws;
    xg_proj2<<<dim3((TT * NB) / 256), dim3(256), 0, stream>>>(
        x, Wih, bih, bhh, xgws);
    gru_rec2<<<dim3(NB), dim3(64), 0, stream>>>(
        xgws, Whh, bhh, Wout, bout, out);
  } else {
    gru57_v4<<<dim3(NB), dim3(64), 0, stream>>>(
        x, Wih, Whh, bih, bhh, Wout, bout, out);
  }
}

// Round 11
// 627.186 us; speedup vs baseline: 1.3348x; 1.0976x over previous
//
#include <hip/hip_runtime.h>
#include <math.h>

#define HH 19
#define NG 57
#define SL 64        // padded slot count per staged xg row (128B lines)
#define NB 1024
#define TT 2048

typedef float v2f __attribute__((ext_vector_type(2)));
typedef float v4f __attribute__((ext_vector_type(4)));
typedef unsigned u2 __attribute__((ext_vector_type(2)));

__device__ __forceinline__ float rlf(float v, int l) {
  return __uint_as_float(__builtin_amdgcn_readlane(__float_as_uint(v), l));
}
__device__ __forceinline__ float frcp(float v) { return __builtin_amdgcn_rcpf(v); }
__device__ __forceinline__ float fexp2(float v) {
#if __has_builtin(__builtin_amdgcn_exp2f)
  return __builtin_amdgcn_exp2f(v);
#else
  return exp2f(v);
#endif
}
__device__ __forceinline__ unsigned short f2h(float f) {
  return __builtin_bit_cast(unsigned short, (_Float16)f);
}
__device__ __forceinline__ float h2f(unsigned short u) {
  return (float)__builtin_bit_cast(_Float16, u);
}
__device__ __forceinline__ v2f mk2(float a, float b) { v2f r; r.x = a; r.y = b; return r; }
__device__ __forceinline__ v2f vfma(v2f a, v2f b, v2f c) {
#if __has_builtin(__builtin_elementwise_fma)
  return __builtin_elementwise_fma(a, b, c);
#else
  v2f r; r.x = fmaf(a.x, b.x, c.x); r.y = fmaf(a.y, b.y, c.y); return r;
#endif
}

#if __has_builtin(__builtin_amdgcn_permlane32_swap)
#define HAVE_PLS 1
__device__ __forceinline__ u2 pls(float x) {
  unsigned u = __float_as_uint(x);
  return __builtin_amdgcn_permlane32_swap(u, u, false, false);
}
#else
#define HAVE_PLS 0
#endif

// ---------------- K1: x-projection, gate-per-lane, 64-slot rows -----------
// xg[pair][slot] f16, slot=lane, 128B aligned coalesced store per pair.
// slot g<38: -log2e*(x·Wih_g + bih_g + bhh_g); g>=38: 2log2e*(x·Wih_g + bih_g).
__global__ __launch_bounds__(256) void xg_proj3(
    const float* __restrict__ x, const float* __restrict__ Wih,
    const float* __restrict__ bih, const float* __restrict__ bhh,
    unsigned short* __restrict__ xg)
{
  const int lane = threadIdx.x & 63;
  const int wv = __builtin_amdgcn_readfirstlane((int)(threadIdx.x >> 6));
  const int g = lane < NG ? lane : NG - 1;
  const float L2E = 1.4426950408889634f;
  const float scale = (g < 2 * HH) ? -L2E : 2.0f * L2E;

  float w[HH];
#pragma unroll
  for (int k = 0; k < HH; ++k) w[k] = Wih[g * HH + k] * scale;
  const float cbv = (bih[g] + (g < 2 * HH ? bhh[g] : 0.0f)) * scale;

  const size_t pair0 = ((size_t)blockIdx.x * 4 + wv) * 64;
  for (int p = 0; p < 64; ++p) {
    const size_t pair = pair0 + p;
    const float* __restrict__ xr = x + pair * HH;   // wave-uniform -> s_load
    float a = cbv;
#pragma unroll
    for (int k = 0; k < HH; ++k) a = fmaf(xr[k], w[k], a);
    xg[pair * SL + lane] = f2h(a);                  // full 128B line
  }
}

// ---------------- K2: recurrence, 57-spread + hidden-latency LDS bcast ----
// lanes 0-18 r-rows (h owners) | 19-31 z 19-31 | 32-50 n 38-56 | 51-56 z 32-37.
// Per step: 1 ushort load, ds_write h -> ds_read_b128 x5 issued immediately
// (same-wave DS is in-order), out-proj of h_{t-2} (double-buffered shA/shB)
// fills the read latency, then one 10-pk dot + activations + 2 permlane
// swaps + 1 z-bpermute. Out stores batched 8/guard.
__global__ void __launch_bounds__(64)
__attribute__((amdgpu_waves_per_eu(1, 1)))
gru_rec3(const unsigned short* __restrict__ xg, const float* __restrict__ Whh,
         const float* __restrict__ bhh, const float* __restrict__ Wout,
         const float* __restrict__ bout, float* __restrict__ out)
{
  __shared__ __align__(16) float hsh[64];
  const int b = blockIdx.x;
  const int lane = threadIdx.x;
  const float L2E = 1.4426950408889634f;

  int row;
  if (lane < 32)      row = lane;
  else if (lane < 51) row = lane + 6;
  else if (lane < 57) row = lane - 19;
  else                row = 37;
  const bool isn = (row >= 2 * HH);
  const float s = isn ? (2.0f * L2E) : -L2E;

  v2f wh2[10], wo2[10];
#pragma unroll
  for (int j = 0; j < 10; ++j) {
    const int k0 = 2 * j, k1 = 2 * j + 1;
    wh2[j].x = s * Whh[row * HH + k0];
    wh2[j].y = (k1 < HH) ? s * Whh[row * HH + k1] : 0.0f;
    wo2[j].x = Wout[k0];
    wo2[j].y = (k1 < HH) ? Wout[k1] : 0.0f;
  }
  const float dinit = isn ? (2.0f * L2E * bhh[row]) : 0.0f;
  const float bo = bout[0];

  const int il = lane < HH ? lane : HH - 1;
  const int zaddr = ((il < 13) ? (19 + il) : (38 + il)) * 4;

#if HAVE_PLS
  bool loIsX;
  {
    unsigned l = (unsigned)lane;
    u2 pr = __builtin_amdgcn_permlane32_swap(l, l, false, false);
    loIsX = ((unsigned)__builtin_amdgcn_readlane((int)pr.x, 32) < 32u);
  }
#define LOBCAST(val, dst) do { u2 _s = pls(val);                        \
    dst = __uint_as_float(loIsX ? _s.x : _s.y); } while (0)
#define HIBCAST(val, dst) do { u2 _s = pls(val);                        \
    dst = __uint_as_float(loIsX ? _s.y : _s.x); } while (0)
#else
  const int loaddr = (lane & 31) * 4;
  const int hiaddr = ((lane & 31) | 32) * 4;
#define LOBCAST(val, dst) dst = __uint_as_float((unsigned)              \
    __builtin_amdgcn_ds_bpermute(loaddr, (int)__float_as_uint(val)))
#define HIBCAST(val, dst) dst = __uint_as_float((unsigned)              \
    __builtin_amdgcn_ds_bpermute(hiaddr, (int)__float_as_uint(val)))
#endif

  float h = 0.0f;                 // lane i<19 owns h_i
  v2f shA[10], shB[10];           // double-buffered h broadcast
#pragma unroll
  for (int j = 0; j < 10; ++j) { shA[j] = mk2(0.f, 0.f); shB[j] = mk2(0.f, 0.f); }

  const unsigned short* __restrict__ xb = xg + (size_t)b * SL + row;
#define LOADX(dst, trow) do { dst = xb[(size_t)(trow) * (NB * SL)]; } while (0)

  unsigned short s0, s1, s2, s3, s4, s5, s6, s7;
  LOADX(s0, 0); LOADX(s1, 1); LOADX(s2, 2); LOADX(s3, 3);
  LOADX(s4, 4); LOADX(s5, 5); LOADX(s6, 6); LOADX(s7, 7);

  // out-projection from a broadcast register set (uniform across lanes)
#define OPROJ(sh, ovar) do {                                            \
    v2f _oA = mk2(bo, 0.f), _oB = mk2(0.f, 0.f);                        \
    _Pragma("unroll")                                                   \
    for (int _j = 0; _j < 5; ++_j)  _oA = vfma(sh[_j], wo2[_j], _oA);   \
    _Pragma("unroll")                                                   \
    for (int _j = 5; _j < 10; ++_j) _oB = vfma(sh[_j], wo2[_j], _oB);   \
    const v2f _ov = _oA + _oB;                                          \
    ovar = _ov.x + _ov.y;                                               \
  } while (0)

#define BODY(tcur, slot, shC, shP, ovar) do {                           \
    /* broadcast h_{t-1}; reads issue right behind the write (DS in-order) */ \
    hsh[lane] = (lane < HH) ? h : 0.0f;                                 \
    const v4f q0 = *(const v4f*)&hsh[0];                                \
    const v4f q1 = *(const v4f*)&hsh[4];                                \
    const v4f q2 = *(const v4f*)&hsh[8];                                \
    const v4f q3 = *(const v4f*)&hsh[12];                               \
    const v4f q4 = *(const v4f*)&hsh[16];                               \
    const float xv = h2f(slot);                                         \
    { const int _tl = ((tcur) + 8 < TT) ? (tcur) + 8 : TT - 1;          \
      LOADX(slot, _tl); }                                               \
    /* latency filler: out-proj of h_{t-2} from regs */                 \
    OPROJ(shP, ovar);                                                   \
    shC[0] = mk2(q0.x, q0.y); shC[1] = mk2(q0.z, q0.w);                 \
    shC[2] = mk2(q1.x, q1.y); shC[3] = mk2(q1.z, q1.w);                 \
    shC[4] = mk2(q2.x, q2.y); shC[5] = mk2(q2.z, q2.w);                 \
    shC[6] = mk2(q3.x, q3.y); shC[7] = mk2(q3.z, q3.w);                 \
    shC[8] = mk2(q4.x, q4.y); shC[9] = mk2(q4.z, q4.w);                 \
    /* per-lane gate dot vs new broadcast */                            \
    v2f _a0 = mk2(dinit, 0.f), _a1 = mk2(0.f, 0.f);                     \
    _Pragma("unroll")                                                   \
    for (int _j = 0; _j < 5; ++_j)  _a0 = vfma(shC[_j], wh2[_j], _a0);  \
    _Pragma("unroll")                                                   \
    for (int _j = 5; _j < 10; ++_j) _a1 = vfma(shC[_j], wh2[_j], _a1);  \
    const v2f _av = _a0 + _a1;                                          \
    const float preh = _av.x + _av.y;                                   \
    const float pre  = xv + preh;            /* r/z lanes */            \
    const float sig  = frcp(fexp2(pre) + 1.0f);                         \
    const int zzi = __builtin_amdgcn_ds_bpermute(                       \
        zaddr, (int)__float_as_uint(sig));                              \
    float rr; LOBCAST(sig, rr);                                         \
    const float arg = fmaf(rr, preh, xv);    /* n lanes */              \
    const float nn = fmaf(-2.0f, frcp(fexp2(arg) + 1.0f), 1.0f);        \
    float nh; HIBCAST(nn, nh);                                          \
    const float zz = __uint_as_float((unsigned)zzi);                    \
    h = fmaf(zz, h - nh, nh);                                           \
  } while (0)

  float o0, o1, o2, o3, o4, o5, o6, o7;
  float* __restrict__ ob = out + b;

  for (int t = 0; t < TT; t += 8) {
    BODY(t + 0, s0, shA, shB, o0);
    BODY(t + 1, s1, shB, shA, o1);
    BODY(t + 2, s2, shA, shB, o2);
    BODY(t + 3, s3, shB, shA, o3);
    BODY(t + 4, s4, shA, shB, o4);
    BODY(t + 5, s5, shB, shA, o5);
    BODY(t + 6, s6, shA, shB, o6);
    BODY(t + 7, s7, shB, shA, o7);
    if (lane == 0) {
      ob[(size_t)(t >= 2 ? t - 2 : 0) * NB] = o0;   // junk at t=0, overwritten
      ob[(size_t)(t >= 1 ? t - 1 : 0) * NB] = o1;   // junk at t=0, overwritten
      ob[(size_t)(t + 0) * NB] = o2;
      ob[(size_t)(t + 1) * NB] = o3;
      ob[(size_t)(t + 2) * NB] = o4;
      ob[(size_t)(t + 3) * NB] = o5;
      ob[(size_t)(t + 4) * NB] = o6;
      ob[(size_t)(t + 5) * NB] = o7;
    }
  }

  // epilogue: out[TT-2] from shB (= h_{TT-2}), out[TT-1] via fresh broadcast
  float oe;
  OPROJ(shB, oe);
  if (lane == 0) ob[(size_t)(TT - 2) * NB] = oe;
  hsh[lane] = (lane < HH) ? h : 0.0f;
  {
    const v4f q0 = *(const v4f*)&hsh[0];
    const v4f q1 = *(const v4f*)&hsh[4];
    const v4f q2 = *(const v4f*)&hsh[8];
    const v4f q3 = *(const v4f*)&hsh[12];
    const v4f q4 = *(const v4f*)&hsh[16];
    shA[0] = mk2(q0.x, q0.y); shA[1] = mk2(q0.z, q0.w);
    shA[2] = mk2(q1.x, q1.y); shA[3] = mk2(q1.z, q1.w);
    shA[4] = mk2(q2.x, q2.y); shA[5] = mk2(q2.z, q2.w);
    shA[6] = mk2(q3.x, q3.y); shA[7] = mk2(q3.z, q3.w);
    shA[8] = mk2(q4.x, q4.y); shA[9] = mk2(q4.z, q4.w);
    OPROJ(shA, oe);
    if (lane == 0) ob[(size_t)(TT - 1) * NB] = oe;
  }
#undef LOADX
#undef BODY
#undef OPROJ
#undef LOBCAST
#undef HIBCAST
}

// ---------------- Fallback: round-8 fused kernel (proven, 555us) ----------
__global__ void __launch_bounds__(64)
__attribute__((amdgpu_waves_per_eu(1, 1)))
gru57_v4(const float* __restrict__ x, const float* __restrict__ Wih,
         const float* __restrict__ Whh, const float* __restrict__ bih,
         const float* __restrict__ bhh, const float* __restrict__ Wout,
         const float* __restrict__ bout, float* __restrict__ out)
{
  const int b = blockIdx.x;
  const int lane = threadIdx.x;
  const float L2E = 1.4426950408889634f;

  int row;
  if (lane < 32)      row = lane;
  else if (lane < 51) row = lane + 6;
  else if (lane < 57) row = lane - 19;
  else                row = 37;
  const bool isn = (row >= 2 * HH);
  const float scale = isn ? (2.0f * L2E) : L2E;

  v2f wx2[10], wh2[10], wo2[10];
#pragma unroll
  for (int j = 0; j < 10; ++j) {
    const int k0 = 2 * j, k1 = 2 * j + 1;
    wx2[j].x = Wih[row * HH + k0] * scale;
    wx2[j].y = (k1 < HH) ? Wih[row * HH + k1] * scale : 0.0f;
    wh2[j].x = Whh[row * HH + k0] * scale;
    wh2[j].y = (k1 < HH) ? Whh[row * HH + k1] * scale : 0.0f;
    wo2[j].x = Wout[k0];
    wo2[j].y = (k1 < HH) ? Wout[k1] : 0.0f;
  }
  const float bxv = bih[row] * scale, bhv = bhh[row] * scale;
  const float ax0 = isn ? bxv : (bxv + bhv);
  const float ah0 = isn ? bhv : 0.0f;
  const float bo  = bout[0];

  const int il = lane < HH ? lane : HH - 1;
  const int zaddr = ((il < 13) ? (19 + il) : (38 + il)) * 4;

#if HAVE_PLS
  bool loIsX;
  {
    unsigned l = (unsigned)lane;
    u2 pr = __builtin_amdgcn_permlane32_swap(l, l, false, false);
    loIsX = ((unsigned)__builtin_amdgcn_readlane((int)pr.x, 32) < 32u);
  }
#define LOBCAST(val, dst) do { u2 _s = pls(val);                        \
    dst = __uint_as_float(loIsX ? _s.x : _s.y); } while (0)
#define HIBCAST(val, dst) do { u2 _s = pls(val);                        \
    dst = __uint_as_float(loIsX ? _s.y : _s.x); } while (0)
#else
  const int loaddr = (lane & 31) * 4;
  const int hiaddr = ((lane & 31) | 32) * 4;
#define LOBCAST(val, dst) dst = __uint_as_float((unsigned)              \
    __builtin_amdgcn_ds_bpermute(loaddr, (int)__float_as_uint(val)))
#define HIBCAST(val, dst) dst = __uint_as_float((unsigned)              \
    __builtin_amdgcn_ds_bpermute(hiaddr, (int)__float_as_uint(val)))
#endif

  float h = 0.0f;
  v2f sh2[10];
#pragma unroll
  for (int j = 0; j < 10; ++j) sh2[j] = mk2(0.f, 0.f);

  const int kx = lane < HH ? lane : HH - 1;
  const float* __restrict__ xbase = x + (size_t)b * HH + kx;

#define LOADXF(dst, trow) do { dst = xbase[(size_t)(trow) * (NB * HH)]; } while (0)
#define XBCAST(slot, xu) do {                                           \
    _Pragma("unroll")                                                   \
    for (int _j = 0; _j < 9; ++_j) {                                    \
      xu[_j].x = rlf(slot, 2 * _j);                                     \
      xu[_j].y = rlf(slot, 2 * _j + 1);                                 \
    }                                                                   \
    xu[9].x = rlf(slot, 18); xu[9].y = 0.0f;                            \
  } while (0)
#define XDOT(xu, dstvar) do {                                           \
    v2f _aA = mk2(ax0, 0.0f), _aB = mk2(0.0f, 0.0f);                    \
    _Pragma("unroll")                                                   \
    for (int _j = 0; _j < 5; ++_j)  _aA = vfma(xu[_j], wx2[_j], _aA);   \
    _Pragma("unroll")                                                   \
    for (int _j = 5; _j < 10; ++_j) _aB = vfma(xu[_j], wx2[_j], _aB);   \
    const v2f _s = _aA + _aB;                                           \
    dstvar = _s.x + _s.y;                                               \
  } while (0)

  float xlA, xlB, xlC, xlD;
  LOADXF(xlA, 0); LOADXF(xlB, 1); LOADXF(xlC, 2); LOADXF(xlD, 3);
  float prex;
  { v2f xu0[10]; XBCAST(xlA, xu0); XDOT(xu0, prex); }

#define BODYF(tcur, nslot, lslot) do {                                  \
    v2f ahA = mk2(ah0, 0.0f), ahB = mk2(0.0f, 0.0f);                    \
    _Pragma("unroll")                                                   \
    for (int _j = 0; _j < 5; ++_j)  ahA = vfma(sh2[_j], wh2[_j], ahA);  \
    _Pragma("unroll")                                                   \
    for (int _j = 5; _j < 10; ++_j) ahB = vfma(sh2[_j], wh2[_j], ahB);  \
    float prexN;                                                        \
    { v2f _xu[10]; XBCAST(nslot, _xu); XDOT(_xu, prexN); }              \
    { const int _tl = ((tcur) + 4 < TT) ? (tcur) + 4 : TT - 1;          \
      LOADXF(lslot, _tl); }                                             \
    const v2f ahv = ahA + ahB;                                          \
    const float preh = ahv.x + ahv.y;                                   \
    const float pre  = prex + preh;                                     \
    const float sig  = frcp(1.0f + fexp2(-pre));                        \
    const int zzi = __builtin_amdgcn_ds_bpermute(                       \
        zaddr, (int)__float_as_uint(sig));                              \
    float rr; LOBCAST(sig, rr);                                         \
    const float npre = fmaf(rr, preh, prex);                            \
    const float nn = fmaf(-2.0f, frcp(fexp2(npre) + 1.0f), 1.0f);       \
    float nh; HIBCAST(nn, nh);                                          \
    const float zz = __uint_as_float((unsigned)zzi);                    \
    h = fmaf(zz, h - nh, nh);                                           \
    _Pragma("unroll")                                                   \
    for (int _j = 0; _j < 9; ++_j) {                                    \
      sh2[_j].x = rlf(h, 2 * _j);                                       \
      sh2[_j].y = rlf(h, 2 * _j + 1);                                   \
    }                                                                   \
    sh2[9].x = rlf(h, 18); sh2[9].y = 0.0f;                             \
    v2f oA = mk2(bo, 0.0f), oB = mk2(0.0f, 0.0f);                       \
    _Pragma("unroll")                                                   \
    for (int _j = 0; _j < 5; ++_j)  oA = vfma(sh2[_j], wo2[_j], oA);    \
    _Pragma("unroll")                                                   \
    for (int _j = 5; _j < 10; ++_j) oB = vfma(sh2[_j], wo2[_j], oB);    \
    const v2f ov = oA + oB;                                             \
    if (lane == 0) out[(size_t)(tcur) * NB + b] = ov.x + ov.y;          \
    prex = prexN;                                                       \
  } while (0)

  for (int t = 0; t < TT; t += 4) {
    BODYF(t + 0, xlB, xlA);
    BODYF(t + 1, xlC, xlB);
    BODYF(t + 2, xlD, xlC);
    BODYF(t + 3, xlA, xlD);
  }

#undef LOADXF
#undef XBCAST
#undef XDOT
#undef BODYF
#undef LOBCAST
#undef HIBCAST
}

extern "C" void kernel_launch(void* const* d_in, const int* in_sizes, int n_in,
                              void* d_out, int out_size, void* d_ws, size_t ws_size,
                              hipStream_t stream) {
  const float* x    = (const float*)d_in[0];
  const float* Wih  = (const float*)d_in[1];
  const float* Whh  = (const float*)d_in[2];
  const float* bih  = (const float*)d_in[3];
  const float* bhh  = (const float*)d_in[4];
  const float* Wout = (const float*)d_in[5];
  const float* bout = (const float*)d_in[6];
  float* out = (float*)d_out;

  const size_t need = (size_t)TT * NB * SL * sizeof(unsigned short);  // 256MB
  if (ws_size >= need) {
    unsigned short* xgws = (unsigned short*)d_ws;
    xg_proj3<<<dim3((TT * NB) / 256), dim3(256), 0, stream>>>(
        x, Wih, bih, bhh, xgws);
    gru_rec3<<<dim3(NB), dim3(64), 0, stream>>>(
        xgws, Whh, bhh, Wout, bout, out);
  } else {
    gru57_v4<<<dim3(NB), dim3(64), 0, stream>>>(
        x, Wih, Whh, bih, bhh, Wout, bout, out);
  }
}